// Round 9
// baseline (113.135 us; speedup 1.0000x reference)
//
#include <hip/hip_runtime.h>

// GraphFilterRNN: u = lsigf(W_D, S, relu(lsigf(W_A,S,x,bA)+lsigf(W_B,S,h,bB)), bD)
// Horner form: per path, u = ((w3 S + w2) S + w1) S + w0,  w_k = A_k x + B_k h.
// B=16, N=1024, E=1, K=4, feature dims all 128.
//
// Round 9: round-8 design with an exactly-finite pipeline (no junk ops,
// vmcnt drains to 0 before s_endpgm — the round-8 fault was junk loads +
// outstanding global_load_lds DMA at wave end). Props: B (S^T) streamed
// global->VGPR from a fragment-major pack; A via 4-slot LDS counted pipeline.

typedef __attribute__((ext_vector_type(8))) short short8;
typedef __attribute__((ext_vector_type(4))) float floatx4;
typedef __attribute__((ext_vector_type(4))) int   intx4;

#define AS1 __attribute__((address_space(1)))
#define AS3 __attribute__((address_space(3)))

__device__ __forceinline__ unsigned short f2bf(float f) {
  union { float f; unsigned u; } v; v.f = f;
  unsigned r = v.u + 0x7fffu + ((v.u >> 16) & 1u);
  return (unsigned short)(r >> 16);
}
__device__ __forceinline__ float bf2f(unsigned short b) {
  union { unsigned u; float f; } v; v.u = ((unsigned)b) << 16;
  return v.f;
}

__device__ __forceinline__ void gload16(const void* g, void* l) {
  __builtin_amdgcn_global_load_lds((const AS1 void*)g, (AS3 void*)l, 16, 0, 0);
}

#define LOADB(dst, p) \
  asm volatile("global_load_dwordx4 %0, %1, off" : "=v"(dst) : "v"(p) : "memory")

union BVU { intx4 i; short8 s; };

// ---------------------------------------------------------------------------
// prop_gemm: C[m,n] = sum_k A[m,k] * Bt[n,k] (+cinit in epilogue), K=1024.
// Tile 64x64, 4 waves, wave-tile 32x32. A: LDS 4-slot, 3-deep, XOR-swizzled
// (pre-swizzled global source). B: fragment-major pack, direct global->VGPR,
// 2-step register prefetch. Finite ledger (per wave, ops in flight):
//   prologue: 6 stage + 8 B = 14; vmcnt(12) -> slot0 A ready.
//   s in [0,15]: stage if s<=12 (2 ops), 4 B if s<=13; waits:
//     s=0:(12,10)  s in[1,12]:(14,12)  s=13:(12,10)  s=14:(6,4)  s=15:(2,0)
//   -> vmcnt==0 at loop exit; no outstanding LDS-DMA at s_endpgm.
// EPI 0: bf16 out (+ci); 2: f32 out (+ci); 4: relu(+ci)->LDS transpose->hnt.
// Grid 512 = 8 XCD * 2 batches * 32 tiles (batch-clustered, bijective).
// ---------------------------------------------------------------------------
template<int EPI>
__global__ __launch_bounds__(256, 2)
void prop_gemm(const unsigned short* __restrict__ A,   // [16][128][1024]
               const unsigned short* __restrict__ Bp,  // packed S^T
               const unsigned short* __restrict__ cinit, long long ciBatch,
               unsigned short* __restrict__ outb, long long obBatch,
               float* __restrict__ outf)
{
  __shared__ unsigned short buf[4][64 * 64];   // A slots, 8KB each

  const int wg  = blockIdx.x;
  const int xcd = wg & 7;
  const int idx = wg >> 3;
  const int b   = xcd * 2 + idx / 32;
  const int r   = idx % 32;
  const int n0  = (r & 15) * 64;
  const int m0  = (r >> 4) * 64;

  const int tid  = threadIdx.x;
  const int wave = tid >> 6;
  const int lane = tid & 63;
  const int wr   = (wave >> 1) * 32;
  const int wc   = (wave & 1) * 32;
  const int l15  = lane & 15;
  const int lhi  = lane >> 4;

  const unsigned short* Ab = A + (long long)b * (128 * 1024);
  const unsigned short* Bb = Bp + (long long)b * (1 << 20);

  // A staging: thread chunks tid, tid+256 (each 16B), source pre-swizzled
  const unsigned short* asrc[2];
  #pragma unroll
  for (int i = 0; i < 2; ++i) {
    const int q  = tid + i * 256;
    const int rr = q >> 3;                       // tile row 0..63
    const int c8 = ((q & 7) ^ (rr & 7)) * 8;     // inverse-swizzled k col
    asrc[i] = Ab + (long long)(m0 + rr) * 1024 + c8;
  }
  auto stageA = [&](int slot, int sidx) {
    #pragma unroll
    for (int i = 0; i < 2; ++i)
      gload16(asrc[i] + sidx * 64, &buf[slot][(tid + i * 256) * 8]);
  };

  // B pointers: two nt panels (each 32 ks x 512 elems) for this wave
  const int nt0 = (n0 >> 4) + (wave & 1) * 2;
  const unsigned short* bp0 = Bb + ((long long)nt0 * 32 * 64 + lane) * 8;
  const unsigned short* bp1 = bp0 + 32 * 64 * 8;

  // A LDS read offsets (swizzled)
  int aoff[2][2];
  #pragma unroll
  for (int kk = 0; kk < 2; ++kk)
    #pragma unroll
    for (int mi = 0; mi < 2; ++mi) {
      const int rowa = wr + mi * 16 + l15;
      aoff[kk][mi] = rowa * 64 + (((kk * 4 + lhi) ^ (rowa & 7)) << 3);
    }

  floatx4 acc[2][2];
  #pragma unroll
  for (int mi = 0; mi < 2; ++mi)
    #pragma unroll
    for (int ni = 0; ni < 2; ++ni)
      acc[mi][ni] = (floatx4){0.f, 0.f, 0.f, 0.f};

  intx4 breg[3][2][2];   // [set][kk][ni]; all indices static after unroll

  // ---- prologue: 6 stage ops + 8 B loads (ks 0..3) ----
  stageA(0, 0); stageA(1, 1); stageA(2, 2);
  LOADB(breg[1][0][0], bp0);        LOADB(breg[1][0][1], bp1);
  LOADB(breg[1][1][0], bp0 + 512);  LOADB(breg[1][1][1], bp1 + 512);
  LOADB(breg[2][0][0], bp0 + 1024); LOADB(breg[2][0][1], bp1 + 1024);
  LOADB(breg[2][1][0], bp0 + 1536); LOADB(breg[2][1][1], bp1 + 1536);
  bp0 += 2048; bp1 += 2048;

  asm volatile("s_waitcnt vmcnt(12)" ::: "memory");   // slot0 A landed
  __builtin_amdgcn_s_barrier();

  #pragma unroll
  for (int s = 0; s < 16; ++s) {
    __builtin_amdgcn_sched_barrier(0);
    if (s + 3 < 16) stageA((s + 3) & 3, s + 3);     // A for step s+3
    if (s < 14) {                                   // B (ks 2s+4, 2s+5) for step s+2
      const int ld = s % 3;
      LOADB(breg[ld][0][0], bp0);       LOADB(breg[ld][0][1], bp1);
      LOADB(breg[ld][1][0], bp0 + 512); LOADB(breg[ld][1][1], bp1 + 512);
      bp0 += 1024; bp1 += 1024;
    }

    const unsigned short* sp = &buf[s & 3][0];
    short8 af0[2], af1[2];
    #pragma unroll
    for (int mi = 0; mi < 2; ++mi) af0[mi] = *(const short8*)(sp + aoff[0][mi]);
    #pragma unroll
    for (int mi = 0; mi < 2; ++mi) af1[mi] = *(const short8*)(sp + aoff[1][mi]);

    const int cs = (s + 1) % 3;
    if (s == 0)       asm volatile("s_waitcnt vmcnt(12)" ::: "memory");
    else if (s <= 12) asm volatile("s_waitcnt vmcnt(14)" ::: "memory");
    else if (s == 13) asm volatile("s_waitcnt vmcnt(12)" ::: "memory");
    else if (s == 14) asm volatile("s_waitcnt vmcnt(6)"  ::: "memory");
    else              asm volatile("s_waitcnt vmcnt(2)"  ::: "memory");
    __builtin_amdgcn_sched_barrier(0);
    {
      BVU u0, u1; u0.i = breg[cs][0][0]; u1.i = breg[cs][0][1];
      __builtin_amdgcn_s_setprio(1);
      acc[0][0] = __builtin_amdgcn_mfma_f32_16x16x32_bf16(af0[0], u0.s, acc[0][0], 0, 0, 0);
      acc[0][1] = __builtin_amdgcn_mfma_f32_16x16x32_bf16(af0[0], u1.s, acc[0][1], 0, 0, 0);
      acc[1][0] = __builtin_amdgcn_mfma_f32_16x16x32_bf16(af0[1], u0.s, acc[1][0], 0, 0, 0);
      acc[1][1] = __builtin_amdgcn_mfma_f32_16x16x32_bf16(af0[1], u1.s, acc[1][1], 0, 0, 0);
      __builtin_amdgcn_s_setprio(0);
    }
    if (s == 0)       asm volatile("s_waitcnt vmcnt(10)" ::: "memory");
    else if (s <= 12) asm volatile("s_waitcnt vmcnt(12)" ::: "memory");
    else if (s == 13) asm volatile("s_waitcnt vmcnt(10)" ::: "memory");
    else if (s == 14) asm volatile("s_waitcnt vmcnt(4)"  ::: "memory");
    else              asm volatile("s_waitcnt vmcnt(0)"  ::: "memory");
    __builtin_amdgcn_sched_barrier(0);
    {
      BVU u0, u1; u0.i = breg[cs][1][0]; u1.i = breg[cs][1][1];
      __builtin_amdgcn_s_setprio(1);
      acc[0][0] = __builtin_amdgcn_mfma_f32_16x16x32_bf16(af1[0], u0.s, acc[0][0], 0, 0, 0);
      acc[0][1] = __builtin_amdgcn_mfma_f32_16x16x32_bf16(af1[0], u1.s, acc[0][1], 0, 0, 0);
      acc[1][0] = __builtin_amdgcn_mfma_f32_16x16x32_bf16(af1[1], u0.s, acc[1][0], 0, 0, 0);
      acc[1][1] = __builtin_amdgcn_mfma_f32_16x16x32_bf16(af1[1], u1.s, acc[1][1], 0, 0, 0);
      __builtin_amdgcn_s_setprio(0);
    }
    if (s < 15) __builtin_amdgcn_s_barrier();   // slot handoff
  }
  // loop exit: vmcnt == 0, no outstanding LDS-DMA.

  if (EPI == 0) {
    const unsigned short* ci = cinit + (long long)b * ciBatch;
    unsigned short* ob = outb + (long long)b * obBatch;
    #pragma unroll
    for (int mi = 0; mi < 2; ++mi)
      #pragma unroll
      for (int ni = 0; ni < 2; ++ni)
        #pragma unroll
        for (int j = 0; j < 4; ++j) {
          const int row = m0 + wr + mi * 16 + lhi * 4 + j;
          const int col = n0 + wc + ni * 16 + l15;
          ob[(long long)row * 1024 + col] =
              f2bf(acc[mi][ni][j] + bf2f(ci[(long long)row * 1024 + col]));
        }
  } else if (EPI == 2) {
    const unsigned short* ci = cinit + (long long)b * ciBatch;
    float* of = outf + (long long)b * (128 * 1024);
    #pragma unroll
    for (int mi = 0; mi < 2; ++mi)
      #pragma unroll
      for (int ni = 0; ni < 2; ++ni)
        #pragma unroll
        for (int j = 0; j < 4; ++j) {
          const int row = m0 + wr + mi * 16 + lhi * 4 + j;
          const int col = n0 + wc + ni * 16 + l15;
          of[(long long)row * 1024 + col] =
              acc[mi][ni][j] + bf2f(ci[(long long)row * 1024 + col]);
        }
  } else {  // EPI == 4: relu(+ci) -> transpose in LDS -> hnt[node][128]
    const unsigned short* ci = cinit + (long long)b * ciBatch;
    __syncthreads();
    unsigned short (*tt)[72] = (unsigned short(*)[72])(&buf[0][0]);
    #pragma unroll
    for (int mi = 0; mi < 2; ++mi)
      #pragma unroll
      for (int ni = 0; ni < 2; ++ni)
        #pragma unroll
        for (int j = 0; j < 4; ++j) {
          const int rowl = wr + mi * 16 + lhi * 4 + j;      // local feat 0..63
          const int coll = wc + ni * 16 + l15;              // local node 0..63
          float v = acc[mi][ni][j] +
                    bf2f(ci[(long long)(m0 + rowl) * 1024 + n0 + coll]);
          tt[coll][rowl] = f2bf(fmaxf(v, 0.f));
        }
    __syncthreads();
    unsigned short* ob = outb + (long long)b * obBatch;     // hnt, stride 128
    #pragma unroll
    for (int i = 0; i < 2; ++i) {
      const int flat = tid + i * 256;     // 0..511 = 64 nodes x 8 segs
      const int node = flat >> 3;
      const int seg  = flat & 7;
      *(short8*)(&ob[(long long)(n0 + node) * 128 + m0 + seg * 8]) =
          *(const short8*)(&tt[node][seg * 8]);
    }
  }
}

// ---------------------------------------------------------------------------
// mix_gemm (round-6 proven form): 64x64 tile, 4 waves, LDS for both operands,
// 4-slot / 3-deep counted vmcnt(8/4/0). M=512 logical, chunk kc=row>>7:
// kc<3 -> cini, kc==3 -> mixv; +bias on kc==0. Grid 2048.
// ---------------------------------------------------------------------------
template<int KK>
__global__ __launch_bounds__(256, 2)
void mix_gemm(const unsigned short* __restrict__ W, int lda,
              const unsigned short* __restrict__ Bt, long long bBatch, int ldb,
              const float* __restrict__ bias,
              unsigned short* __restrict__ cini,
              unsigned short* __restrict__ mixv)
{
  constexpr int NT = KK / 64;
  __shared__ unsigned short buf[4][128 * 64];

  const int wg  = blockIdx.x;
  const int xcd = wg & 7;
  const int idx = wg >> 3;
  const int b   = xcd * 2 + idx / 128;
  const int r   = idx % 128;
  const int n0  = (r & 15) * 64;
  const int m0  = (r >> 4) * 64;

  const int tid  = threadIdx.x;
  const int wave = tid >> 6;
  const int lane = tid & 63;
  const int wr   = (wave >> 1) * 32;
  const int wc   = (wave & 1) * 32;
  const int l15  = lane & 15;
  const int lhi  = lane >> 4;

  const unsigned short* Bb = Bt + (long long)b * bBatch;

  const unsigned short* src[4];
  int ldsoff[4];
  #pragma unroll
  for (int i = 0; i < 4; ++i) {
    const int u  = wave * 4 + i;
    const int q  = u * 64 + lane;
    const int rr = q >> 3;
    const int c8 = ((q & 7) ^ (rr & 7)) * 8;
    src[i] = (rr < 64) ? W + (long long)(m0 + rr) * lda + c8
                       : Bb + (long long)(n0 + rr - 64) * ldb + c8;
    ldsoff[i] = u * 512;
  }
  auto stage = [&](int slot) {
    #pragma unroll
    for (int i = 0; i < 4; ++i) {
      gload16(src[i], &buf[slot][ldsoff[i]]);
      src[i] += 64;
    }
  };

  int aoff[2][2], boff[2][2];
  #pragma unroll
  for (int kk = 0; kk < 2; ++kk) {
    #pragma unroll
    for (int mi = 0; mi < 2; ++mi) {
      const int rowa = wr + mi * 16 + l15;
      aoff[kk][mi] = rowa * 64 + (((kk * 4 + lhi) ^ (rowa & 7)) << 3);
    }
    #pragma unroll
    for (int ni = 0; ni < 2; ++ni) {
      const int rowb = 64 + wc + ni * 16 + l15;
      boff[kk][ni] = rowb * 64 + (((kk * 4 + lhi) ^ (rowb & 7)) << 3);
    }
  }

  floatx4 acc[2][2];
  #pragma unroll
  for (int mi = 0; mi < 2; ++mi)
    #pragma unroll
    for (int ni = 0; ni < 2; ++ni)
      acc[mi][ni] = (floatx4){0.f, 0.f, 0.f, 0.f};

  stage(0);
  if (NT > 1) stage(1);
  if (NT > 2) stage(2);

  #pragma unroll
  for (int t = 0; t < NT; ++t) {
    const int rem = NT - 1 - t;
    if (rem >= 2)      asm volatile("s_waitcnt vmcnt(8)" ::: "memory");
    else if (rem == 1) asm volatile("s_waitcnt vmcnt(4)" ::: "memory");
    else               asm volatile("s_waitcnt vmcnt(0)" ::: "memory");
    __builtin_amdgcn_s_barrier();
    __builtin_amdgcn_sched_barrier(0);
    if (t + 3 < NT) stage((t + 3) & 3);

    const unsigned short* bp = &buf[t & 3][0];
    #pragma unroll
    for (int kk = 0; kk < 2; ++kk) {
      short8 af[2], bv[2];
      #pragma unroll
      for (int mi = 0; mi < 2; ++mi) af[mi] = *(const short8*)(bp + aoff[kk][mi]);
      #pragma unroll
      for (int ni = 0; ni < 2; ++ni) bv[ni] = *(const short8*)(bp + boff[kk][ni]);
      __builtin_amdgcn_s_setprio(1);
      #pragma unroll
      for (int mi = 0; mi < 2; ++mi)
        #pragma unroll
        for (int ni = 0; ni < 2; ++ni)
          acc[mi][ni] = __builtin_amdgcn_mfma_f32_16x16x32_bf16(af[mi], bv[ni], acc[mi][ni], 0, 0, 0);
      __builtin_amdgcn_s_setprio(0);
    }
  }

  #pragma unroll
  for (int mi = 0; mi < 2; ++mi)
    #pragma unroll
    for (int ni = 0; ni < 2; ++ni)
      #pragma unroll
      for (int j = 0; j < 4; ++j) {
        const int gr = m0 + wr + mi * 16 + lhi * 4 + j;   // 0..511
        const int kc = gr >> 7;
        const int rl = gr & 127;
        const int col = n0 + wc + ni * 16 + l15;
        unsigned short* dst = (kc == 3) ? (mixv + (long long)b * (128 * 1024))
                                        : (cini + (long long)b * (3LL * 128 * 1024) + kc * (128 * 1024));
        float v = acc[mi][ni][j];
        if (kc == 0) v += bias[rl];
        dst[(long long)rl * 1024 + col] = f2bf(v);
      }
}

// ---------------------------------------------------------------------------
// prep_all: weight pack (W1/W2/biasAB) + S -> Bpack (fragment-major S^T bf16)
// + [x;h]^T -> z0t bf16. 512 blocks, batch-clustered, small LDS.
// Bpack elem (n,k) at ((n>>4)*32 + (k>>5))*512 + ((n&15)+16*((k>>3)&3))*8 + (k&7)
// ---------------------------------------------------------------------------
__global__ __launch_bounds__(256)
void prep_all(const float* __restrict__ x, const float* __restrict__ hid,
              const float* __restrict__ S,
              const float* __restrict__ wA, const float* __restrict__ wB,
              const float* __restrict__ wD,
              const float* __restrict__ bA, const float* __restrict__ bB,
              unsigned short* __restrict__ Bpack, unsigned short* __restrict__ z0t,
              unsigned short* __restrict__ W1, unsigned short* __restrict__ W2,
              float* __restrict__ biasAB)
{
  __shared__ float t[64][65];
  const int wg  = blockIdx.x;          // 0..511
  const int tid = threadIdx.x;

  // ---- weight pack ----
  #pragma unroll
  for (int k = 0; k < 2; ++k) {
    const int i = wg * 512 + k * 256 + tid;
    if (i < 512 * 256) {
      const int row = i >> 8, g2 = i & 255;
      const int kk = row >> 7, h = row & 127;
      const float v = (g2 < 128) ? wA[(h * 4 + kk) * 128 + g2]
                                 : wB[(h * 4 + kk) * 128 + (g2 - 128)];
      W1[i] = f2bf(v);
    } else if (i < 512 * 256 + 512 * 128) {
      const int j = i - 512 * 256;
      const int row = j >> 7, h2 = j & 127;
      const int kk = row >> 7, f = row & 127;
      W2[j] = f2bf(wD[(f * 4 + kk) * 128 + h2]);
    } else if (i < 512 * 256 + 512 * 128 + 128) {
      const int l = i - 512 * 256 - 512 * 128;
      biasAB[l] = bA[l] + bB[l];
    }
  }

  const int b  = (wg & 7) * 2 + (wg >> 3) / 32;
  const int jj = (wg >> 3) % 32;       // 0..31 within batch
  const int tx = tid & 63;
  const int ty = tid >> 6;

  // ---- S -> Bpack: 8 of the 256 64x64 tiles of this batch ----
  const float* Sb = S + (long long)b * (1024 * 1024);
  unsigned short* Bpb = Bpack + (long long)b * (1 << 20);
  for (int q = 0; q < 8; ++q) {
    const int tile = jj * 8 + q;               // 0..255
    const int c0 = (tile & 15) * 64;           // n-range base
    const int r0 = (tile >> 4) * 64;           // k-range base
    __syncthreads();
    #pragma unroll
    for (int i = 0; i < 64; i += 4)            // t[k_local][n_local]
      t[ty + i][tx] = Sb[(long long)(r0 + ty + i) * 1024 + c0 + tx];
    __syncthreads();
    #pragma unroll
    for (int w2 = 0; w2 < 2; ++w2) {
      const int u  = tid + w2 * 256;           // 0..511 lane-slots
      const int p  = u >> 6;                   // panel 0..7
      const int l  = u & 63;
      const int nl = (p & 3) * 16 + (l & 15);
      const int kl = (p >> 2) * 32 + (l >> 4) * 8;
      unsigned vv[4];
      #pragma unroll
      for (int e = 0; e < 4; ++e) {
        const unsigned lo = f2bf(t[kl + 2 * e][nl]);
        const unsigned hi = f2bf(t[kl + 2 * e + 1][nl]);
        vv[e] = lo | (hi << 16);
      }
      const long long nt_g = (c0 >> 4) + (p & 3);
      const long long ks_g = (r0 >> 5) + (p >> 2);
      uint4* dst = (uint4*)(Bpb + (nt_g * 32 + ks_g) * 512 + l * 8);
      *dst = (uint4){vv[0], vv[1], vv[2], vv[3]};
    }
  }

  // ---- [x;h]^T -> z0t [node][256] ----
  unsigned short* zb = z0t + (long long)b * (1024 * 256);
  for (int q = 0; q < 2; ++q) {
    const int idx2 = jj * 2 + q;               // 0..63
    const int srch = idx2 >> 5;                // 0: x, 1: hidden
    const int t2   = idx2 & 31;
    const int c0 = (t2 & 15) * 64, r0 = ((t2 >> 4) & 1) * 64;
    const float* sp = (srch ? hid : x) + (long long)b * (128 * 1024);
    __syncthreads();
    #pragma unroll
    for (int i = 0; i < 64; i += 4)
      t[ty + i][tx] = sp[(long long)(r0 + ty + i) * 1024 + c0 + tx];
    __syncthreads();
    #pragma unroll
    for (int i = 0; i < 64; i += 4)
      zb[(long long)(c0 + ty + i) * 256 + srch * 128 + r0 + tx] = f2bf(t[tx][ty + i]);
  }
}

// ---------------------------------------------------------------------------
extern "C" void kernel_launch(void* const* d_in, const int* in_sizes, int n_in,
                              void* d_out, int out_size, void* d_ws, size_t ws_size,
                              hipStream_t stream)
{
  const float* x   = (const float*)d_in[0];
  const float* hid = (const float*)d_in[1];
  const float* S   = (const float*)d_in[2];
  const float* wA  = (const float*)d_in[3];
  const float* wB  = (const float*)d_in[4];
  const float* wD  = (const float*)d_in[5];
  const float* bA  = (const float*)d_in[6];
  const float* bB  = (const float*)d_in[7];
  const float* bD  = (const float*)d_in[8];
  float* out = (float*)d_out;

  char* ws = (char*)d_ws;
  auto alloc = [&](size_t bytes) {
    char* p = ws;
    ws += (bytes + 255) & ~(size_t)255;
    return p;
  };
  unsigned short* Bpack = (unsigned short*)alloc(16ull * (1 << 20) * 2);     // packed S^T
  unsigned short* z0t  = (unsigned short*)alloc(16ull * 1024 * 256 * 2);     // [x;h]^T
  unsigned short* cini = (unsigned short*)alloc(16ull * 3 * 128 * 1024 * 2); // w/d chunks 0..2
  unsigned short* vb0  = (unsigned short*)alloc(16ull * 128 * 1024 * 2);
  unsigned short* vb1  = (unsigned short*)alloc(16ull * 128 * 1024 * 2);
  unsigned short* hnt  = (unsigned short*)alloc(16ull * 1024 * 128 * 2);     // h_next^T node-major
  unsigned short* W1   = (unsigned short*)alloc(512 * 256 * 2);
  unsigned short* W2   = (unsigned short*)alloc(512 * 128 * 2);
  float*          bAB  = (float*)alloc(128 * 4);

  const long long NB  = 128 * 1024;    // per-batch [128][1024]
  const long long NB2 = 1024 * 128;    // per-batch [1024][128]
  const long long CI  = 3 * NB;        // cinit batch stride

  prep_all<<<dim3(512), 256, 0, stream>>>(x, hid, S, wA, wB, wD, bA, bB,
                                          Bpack, z0t, W1, W2, bAB);

  // mix1: w_k = [A_k|B_k] @ [x;h]  (k=3 -> vb0, k<3 -> cini, k=0 += bA+bB)
  mix_gemm<256><<<dim3(2048), 256, 0, stream>>>(W1, 256, z0t, 1024 * 256, 256,
      bAB, cini, vb0);
  // Horner phase 1: v = ((w3 S + w2) S + w1) S + w0 ; h_next^T = relu(...)^T
  prop_gemm<0><<<dim3(512), 256, 0, stream>>>(vb0, Bpack, cini + 2 * NB, CI,
      vb1, NB, nullptr);
  prop_gemm<0><<<dim3(512), 256, 0, stream>>>(vb1, Bpack, cini + 1 * NB, CI,
      vb0, NB, nullptr);
  prop_gemm<4><<<dim3(512), 256, 0, stream>>>(vb0, Bpack, cini, CI,
      hnt, NB2, nullptr);

  // mix2: d_k = D_k @ h_next  (k=3 -> vb0, k<3 -> cini, k=0 += bD)
  mix_gemm<128><<<dim3(2048), 256, 0, stream>>>(W2, 128, hnt, NB2, 128,
      bD, cini, vb0);
  // Horner phase 2: out = ((d3 S + d2) S + d1) S + d0
  prop_gemm<0><<<dim3(512), 256, 0, stream>>>(vb0, Bpack, cini + 2 * NB, CI,
      vb1, NB, nullptr);
  prop_gemm<0><<<dim3(512), 256, 0, stream>>>(vb1, Bpack, cini + 1 * NB, CI,
      vb0, NB, nullptr);
  prop_gemm<2><<<dim3(512), 256, 0, stream>>>(vb0, Bpack, cini, CI,
      nullptr, 0, out);
}

// Round 11
// 103.505 us; speedup vs baseline: 1.0930x; 1.0930x over previous
//
#include <hip/hip_runtime.h>

// GraphFilterRNN: u = lsigf(W_D, S, relu(lsigf(W_A,S,x,bA)+lsigf(W_B,S,h,bB)), bD)
// Horner form: per path, u = ((w3 S + w2) S + w1) S + w0,  w_k = A_k x + B_k h.
// B=16, N=1024, E=1, K=4, feature dims all 128.
//
// Round 11: round-6 chain (prep_all fused; proven 107.3us) with the GEMMs at
// 3 LDS slots / 2-deep prefetch / 3 blocks/CU (48KB LDS, launch_bounds(256,3))
// -- A/B vs round-6's 4-slot/2-blocks. Ledger: per K-step vmcnt(4) (last 0),
// s_barrier, stage((t+2)%3). Everything else identical to round 6.

typedef __attribute__((ext_vector_type(8))) short short8;
typedef __attribute__((ext_vector_type(4))) float floatx4;

#define AS1 __attribute__((address_space(1)))
#define AS3 __attribute__((address_space(3)))

__device__ __forceinline__ unsigned short f2bf(float f) {
  union { float f; unsigned u; } v; v.f = f;
  unsigned r = v.u + 0x7fffu + ((v.u >> 16) & 1u);
  return (unsigned short)(r >> 16);
}
__device__ __forceinline__ float bf2f(unsigned short b) {
  union { unsigned u; float f; } v; v.u = ((unsigned)b) << 16;
  return v.f;
}

__device__ __forceinline__ void gload16(const void* g, void* l) {
  __builtin_amdgcn_global_load_lds((const AS1 void*)g, (AS3 void*)l, 16, 0, 0);
}

// ---------------------------------------------------------------------------
// GEMM: C[m,n] = sum_k A[m,k]*Bt[n,k] (+cinit in epilogue).
// Tile 64x64, BK=64, 4 waves, wave-tile 32x32 (2x2 acc).
// LDS: 3 slots of 128 rows x 64 k (A rows 0..63, B rows 64..127), XOR-swizzle
// via pre-swizzled global source + swizzled ds_read (linear gload_lds dest).
// Pipeline: 2-deep prefetch; per K-step: vmcnt(4) counted wait (0 at last),
// raw s_barrier, stage((t+2)%3), ds_read + setprio-wrapped MFMA.
// EPI 0: bf16 out (+ci); 2: f32 out (+ci); 3: mix (chunk dest, +bias kc0);
// EPI 4: relu(+ci) -> LDS transpose -> node-major bf16 (h_next^T).
// Grid: 1-D; XCD batch-cluster swizzle (bijective; 2 batches/XCD).
// ---------------------------------------------------------------------------
template<int EPI, int KK>
__global__ __launch_bounds__(256, 3)
void gemm_bt(const unsigned short* __restrict__ A, long long aBatch, int lda,
             const unsigned short* __restrict__ Bt, long long bBatch, int ldb,
             const unsigned short* __restrict__ cinit, long long ciBatch,
             const float* __restrict__ bias,
             unsigned short* __restrict__ outb, long long obBatch,
             float* __restrict__ outf, long long ofBatch,
             unsigned short* __restrict__ mixv, long long mvBatch)
{
  constexpr int NT   = KK / 64;
  constexpr int MT   = (EPI == 3) ? 8 : 2;   // m-tiles (M=512 mixes, else 128)
  constexpr int PERB = 16 * MT;              // blocks per batch
  __shared__ unsigned short buf[3][128 * 64];

  // XCD batch-cluster swizzle (bijective; 2 batches per XCD)
  const int wg  = blockIdx.x;
  const int xcd = wg & 7;
  const int idx = wg >> 3;
  const int b   = xcd * 2 + idx / PERB;
  const int r   = idx % PERB;
  const int n0  = (r & 15) * 64;
  const int m0  = (r >> 4) * 64;

  const int tid  = threadIdx.x;
  const int wave = tid >> 6;
  const int lane = tid & 63;
  const int wr   = (wave >> 1) * 32;
  const int wc   = (wave & 1) * 32;
  const int l15  = lane & 15;
  const int lhi  = lane >> 4;

  const unsigned short* Ab = A + (long long)b * aBatch;
  const unsigned short* Bb = Bt + (long long)b * bBatch;

  // per-thread staging sources (advance by 64 elems per staged tile)
  const unsigned short* src[4];
  int ldsoff[4];
  #pragma unroll
  for (int i = 0; i < 4; ++i) {
    const int u  = wave * 4 + i;                // 0..15
    const int q  = u * 64 + lane;               // 0..1023
    const int rr = q >> 3;                      // combined row 0..127
    const int c8 = ((q & 7) ^ (rr & 7)) * 8;    // inverse-swizzled k col
    src[i] = (rr < 64) ? Ab + (long long)(m0 + rr) * lda + c8
                       : Bb + (long long)(n0 + rr - 64) * ldb + c8;
    ldsoff[i] = u * 512;
  }
  auto stage = [&](int slot) {
    #pragma unroll
    for (int i = 0; i < 4; ++i) {
      gload16(src[i], &buf[slot][ldsoff[i]]);
      src[i] += 64;
    }
  };

  // per-thread LDS read offsets (within a slot)
  int aoff[2][2], boff[2][2];
  #pragma unroll
  for (int kk = 0; kk < 2; ++kk) {
    #pragma unroll
    for (int mi = 0; mi < 2; ++mi) {
      const int rowa = wr + mi * 16 + l15;
      aoff[kk][mi] = rowa * 64 + (((kk * 4 + lhi) ^ (rowa & 7)) << 3);
    }
    #pragma unroll
    for (int ni = 0; ni < 2; ++ni) {
      const int rowb = 64 + wc + ni * 16 + l15;
      boff[kk][ni] = rowb * 64 + (((kk * 4 + lhi) ^ (rowb & 7)) << 3);
    }
  }

  floatx4 acc[2][2];
  #pragma unroll
  for (int mi = 0; mi < 2; ++mi)
    #pragma unroll
    for (int ni = 0; ni < 2; ++ni)
      acc[mi][ni] = (floatx4){0.f, 0.f, 0.f, 0.f};

  stage(0);
  if (NT > 1) stage(1);

  #pragma unroll
  for (int t = 0; t < NT; ++t) {
    // retire tile t's 4 loads; keep tile t+1's 4 in flight
    if (t + 1 < NT) { asm volatile("s_waitcnt vmcnt(4)" ::: "memory"); }
    else            { asm volatile("s_waitcnt vmcnt(0)" ::: "memory"); }
    __builtin_amdgcn_s_barrier();          // all waves' tile-t loads landed;
    __builtin_amdgcn_sched_barrier(0);     // all tile-(t-1) reads consumed
    if (t + 2 < NT) stage((t + 2) % 3);    // overwrites slot (t-1)%3

    const unsigned short* bp = &buf[t % 3][0];
    #pragma unroll
    for (int kk = 0; kk < 2; ++kk) {
      short8 af[2], bv[2];
      #pragma unroll
      for (int mi = 0; mi < 2; ++mi) af[mi] = *(const short8*)(bp + aoff[kk][mi]);
      #pragma unroll
      for (int ni = 0; ni < 2; ++ni) bv[ni] = *(const short8*)(bp + boff[kk][ni]);
      __builtin_amdgcn_s_setprio(1);
      #pragma unroll
      for (int mi = 0; mi < 2; ++mi)
        #pragma unroll
        for (int ni = 0; ni < 2; ++ni)
          acc[mi][ni] = __builtin_amdgcn_mfma_f32_16x16x32_bf16(af[mi], bv[ni], acc[mi][ni], 0, 0, 0);
      __builtin_amdgcn_s_setprio(0);
    }
  }
  // loop exit: vmcnt == 0, all LDS reads consumed.

  if (EPI == 0) {
    const unsigned short* ci = cinit + (long long)b * ciBatch;
    unsigned short* ob = outb + (long long)b * obBatch;
    #pragma unroll
    for (int mi = 0; mi < 2; ++mi)
      #pragma unroll
      for (int ni = 0; ni < 2; ++ni)
        #pragma unroll
        for (int j = 0; j < 4; ++j) {
          const int row = m0 + wr + mi * 16 + lhi * 4 + j;
          const int col = n0 + wc + ni * 16 + l15;
          ob[(long long)row * 1024 + col] =
              f2bf(acc[mi][ni][j] + bf2f(ci[(long long)row * 1024 + col]));
        }
  } else if (EPI == 2) {
    const unsigned short* ci = cinit + (long long)b * ciBatch;
    float* of = outf + (long long)b * ofBatch;
    #pragma unroll
    for (int mi = 0; mi < 2; ++mi)
      #pragma unroll
      for (int ni = 0; ni < 2; ++ni)
        #pragma unroll
        for (int j = 0; j < 4; ++j) {
          const int row = m0 + wr + mi * 16 + lhi * 4 + j;
          const int col = n0 + wc + ni * 16 + l15;
          of[(long long)row * 1024 + col] =
              acc[mi][ni][j] + bf2f(ci[(long long)row * 1024 + col]);
        }
  } else if (EPI == 3) {  // mix: logical M=512; chunk kc = row>>7
    #pragma unroll
    for (int mi = 0; mi < 2; ++mi)
      #pragma unroll
      for (int ni = 0; ni < 2; ++ni)
        #pragma unroll
        for (int j = 0; j < 4; ++j) {
          const int gr = m0 + wr + mi * 16 + lhi * 4 + j;   // 0..511
          const int kc = gr >> 7;
          const int rl = gr & 127;
          const int col = n0 + wc + ni * 16 + l15;
          unsigned short* dst = (kc == 3) ? (mixv + (long long)b * mvBatch)
                                          : (outb + (long long)b * obBatch + kc * (128 * 1024));
          float v = acc[mi][ni][j];
          if (kc == 0 && bias != nullptr) v += bias[rl];
          dst[(long long)rl * 1024 + col] = f2bf(v);
        }
  } else {  // EPI == 4: relu(+ci) -> transpose in LDS -> hnt[node][128]
    const unsigned short* ci = cinit + (long long)b * ciBatch;
    __syncthreads();   // all LDS reads consumed; vmcnt already 0
    unsigned short (*tt)[72] = (unsigned short(*)[72])(&buf[0][0]); // 9216B < slot0
    #pragma unroll
    for (int mi = 0; mi < 2; ++mi)
      #pragma unroll
      for (int ni = 0; ni < 2; ++ni)
        #pragma unroll
        for (int j = 0; j < 4; ++j) {
          const int rowl = wr + mi * 16 + lhi * 4 + j;      // local feat 0..63
          const int coll = wc + ni * 16 + l15;              // local node 0..63
          float v = acc[mi][ni][j] +
                    bf2f(ci[(long long)(m0 + rowl) * 1024 + n0 + coll]);
          tt[coll][rowl] = f2bf(fmaxf(v, 0.f));
        }
    __syncthreads();
    unsigned short* ob = outb + (long long)b * obBatch;     // hnt, stride 128
    #pragma unroll
    for (int i = 0; i < 2; ++i) {
      const int flat = tid + i * 256;     // 0..511 = 64 nodes x 8 segs
      const int node = flat >> 3;
      const int seg  = flat & 7;
      *(short8*)(&ob[(long long)(n0 + node) * 128 + m0 + seg * 8]) =
          *(const short8*)(&tt[node][seg * 8]);
    }
  }
}

// ---------------------------------------------------------------------------
// prep_all: one kernel, 512 blocks, batch-clustered (round-6 proven).
//  (a) weight pack W1/W2/biasAB  (b) S -> S^T bf16  (c) [x;h] -> z0t bf16
// ---------------------------------------------------------------------------
__global__ __launch_bounds__(256)
void prep_all(const float* __restrict__ x, const float* __restrict__ hid,
              const float* __restrict__ S,
              const float* __restrict__ wA, const float* __restrict__ wB,
              const float* __restrict__ wD,
              const float* __restrict__ bA, const float* __restrict__ bB,
              unsigned short* __restrict__ St, unsigned short* __restrict__ z0t,
              unsigned short* __restrict__ W1, unsigned short* __restrict__ W2,
              float* __restrict__ biasAB)
{
  __shared__ float t[64][65];
  const int wg  = blockIdx.x;          // 0..511
  const int tid = threadIdx.x;

  // ---- weight pack: 196736 elems over 512 blocks x 512 ----
  #pragma unroll
  for (int k = 0; k < 2; ++k) {
    const int i = wg * 512 + k * 256 + tid;
    if (i < 512 * 256) {
      const int row = i >> 8, g2 = i & 255;
      const int kk = row >> 7, h = row & 127;
      const float v = (g2 < 128) ? wA[(h * 4 + kk) * 128 + g2]
                                 : wB[(h * 4 + kk) * 128 + (g2 - 128)];
      W1[i] = f2bf(v);
    } else if (i < 512 * 256 + 512 * 128) {
      const int j = i - 512 * 256;
      const int row = j >> 7, h2 = j & 127;
      const int kk = row >> 7, f = row & 127;
      W2[j] = f2bf(wD[(f * 4 + kk) * 128 + h2]);
    } else if (i < 512 * 256 + 512 * 128 + 128) {
      const int l = i - 512 * 256 - 512 * 128;
      biasAB[l] = bA[l] + bB[l];
    }
  }

  // batch-cluster mapping: 32 blocks per batch, batch pinned to XCD pair
  const int b  = (wg & 7) * 2 + (wg >> 3) / 32;
  const int jj = (wg >> 3) % 32;       // 0..31 within batch
  const int tx = tid & 63;
  const int ty = tid >> 6;             // 0..3

  // ---- S^T: 8 of the 256 64x64 tiles of this batch ----
  const float* Sb = S + (long long)b * (1024 * 1024);
  unsigned short* Stb = St + (long long)b * (1024 * 1024);
  for (int q = 0; q < 8; ++q) {
    const int tile = jj * 8 + q;               // 0..255
    const int c0 = (tile & 15) * 64, r0 = (tile >> 4) * 64;
    __syncthreads();
    #pragma unroll
    for (int i = 0; i < 64; i += 4)
      t[ty + i][tx] = Sb[(long long)(r0 + ty + i) * 1024 + c0 + tx];
    __syncthreads();
    #pragma unroll
    for (int i = 0; i < 64; i += 4)
      Stb[(long long)(c0 + ty + i) * 1024 + r0 + tx] = f2bf(t[tx][ty + i]);
  }

  // ---- [x;h]^T: 2 of the 64 tiles of this batch ----
  unsigned short* zb = z0t + (long long)b * (1024 * 256);
  for (int q = 0; q < 2; ++q) {
    const int idx2 = jj * 2 + q;               // 0..63
    const int srch = idx2 >> 5;                // 0: x, 1: hidden
    const int t2   = idx2 & 31;
    const int c0 = (t2 & 15) * 64, r0 = ((t2 >> 4) & 1) * 64;
    const float* sp = (srch ? hid : x) + (long long)b * (128 * 1024);
    __syncthreads();
    #pragma unroll
    for (int i = 0; i < 64; i += 4)
      t[ty + i][tx] = sp[(long long)(r0 + ty + i) * 1024 + c0 + tx];
    __syncthreads();
    #pragma unroll
    for (int i = 0; i < 64; i += 4)
      zb[(long long)(c0 + ty + i) * 256 + srch * 128 + r0 + tx] = f2bf(t[tx][ty + i]);
  }
}

// ---------------------------------------------------------------------------
extern "C" void kernel_launch(void* const* d_in, const int* in_sizes, int n_in,
                              void* d_out, int out_size, void* d_ws, size_t ws_size,
                              hipStream_t stream)
{
  const float* x   = (const float*)d_in[0];
  const float* hid = (const float*)d_in[1];
  const float* S   = (const float*)d_in[2];
  const float* wA  = (const float*)d_in[3];
  const float* wB  = (const float*)d_in[4];
  const float* wD  = (const float*)d_in[5];
  const float* bA  = (const float*)d_in[6];
  const float* bB  = (const float*)d_in[7];
  const float* bD  = (const float*)d_in[8];
  float* out = (float*)d_out;

  char* ws = (char*)d_ws;
  auto alloc = [&](size_t bytes) {
    char* p = ws;
    ws += (bytes + 255) & ~(size_t)255;
    return p;
  };
  unsigned short* St   = (unsigned short*)alloc(16ull * 1024 * 1024 * 2); // S^T bf16
  unsigned short* z0t  = (unsigned short*)alloc(16ull * 1024 * 256 * 2);  // [x;h]^T bf16
  unsigned short* cini = (unsigned short*)alloc(16ull * 3 * 128 * 1024 * 2); // w_0..2 / d_0..2
  unsigned short* vb0  = (unsigned short*)alloc(16ull * 128 * 1024 * 2);
  unsigned short* vb1  = (unsigned short*)alloc(16ull * 128 * 1024 * 2);
  unsigned short* hnt  = (unsigned short*)alloc(16ull * 1024 * 128 * 2);  // h_next^T (node-major)
  unsigned short* W1   = (unsigned short*)alloc(512 * 256 * 2);
  unsigned short* W2   = (unsigned short*)alloc(512 * 128 * 2);
  float*          bAB  = (float*)alloc(128 * 4);

  const long long NB  = 128 * 1024;    // per-batch [128][1024]
  const long long NB2 = 1024 * 128;    // per-batch [1024][128]
  const long long CI  = 3 * NB;        // cinit batch stride
  const long long SB  = 1024 * 1024;   // S batch stride

  prep_all<<<dim3(512), 256, 0, stream>>>(x, hid, S, wA, wB, wD, bA, bB,
                                          St, z0t, W1, W2, bAB);

  // mix1: w_k = [A_k|B_k] @ [x;h]  (k=3 -> vb0, k<3 -> cini, k=0 += bA+bB)
  gemm_bt<3, 256><<<dim3(2048), 256, 0, stream>>>(W1, 0, 256, z0t, 1024 * 256, 256,
      nullptr, 0, bAB, cini, CI, nullptr, 0, vb0, NB);
  // Horner phase 1: v = ((w3 S + w2) S + w1) S + w0 ; h_next^T = relu(...)^T
  gemm_bt<0, 1024><<<dim3(512), 256, 0, stream>>>(vb0, NB, 1024, St, SB, 1024,
      cini + 2 * NB, CI, nullptr, vb1, NB, nullptr, 0, nullptr, 0);
  gemm_bt<0, 1024><<<dim3(512), 256, 0, stream>>>(vb1, NB, 1024, St, SB, 1024,
      cini + 1 * NB, CI, nullptr, vb0, NB, nullptr, 0, nullptr, 0);
  gemm_bt<4, 1024><<<dim3(512), 256, 0, stream>>>(vb0, NB, 1024, St, SB, 1024,
      cini, CI, nullptr, hnt, NB2, nullptr, 0, nullptr, 0);

  // mix2: d_k = D_k @ h_next  (k=3 -> vb0, k<3 -> cini, k=0 += bD)
  gemm_bt<3, 128><<<dim3(2048), 256, 0, stream>>>(W2, 0, 128, hnt, NB2, 128,
      nullptr, 0, bD, cini, CI, nullptr, 0, vb0, NB);
  // Horner phase 2: out = ((d3 S + d2) S + d1) S + d0
  gemm_bt<0, 1024><<<dim3(512), 256, 0, stream>>>(vb0, NB, 1024, St, SB, 1024,
      cini + 2 * NB, CI, nullptr, vb1, NB, nullptr, 0, nullptr, 0);
  gemm_bt<0, 1024><<<dim3(512), 256, 0, stream>>>(vb1, NB, 1024, St, SB, 1024,
      cini + 1 * NB, CI, nullptr, vb0, NB, nullptr, 0, nullptr, 0);
  gemm_bt<2, 1024><<<dim3(512), 256, 0, stream>>>(vb0, NB, 1024, St, SB, 1024,
      cini, CI, nullptr, nullptr, 0, out, NB, nullptr, 0);
}